// Round 7
// baseline (186.938 us; speedup 1.0000x reference)
//
#include <hip/hip_runtime.h>
#include <hip/hip_bf16.h>

#define N_NODES 50000
#define N_EDGES 500000
#define D 128
#define NUM_GRAPHS 512
#define BM 128
#define NB_NODES 196      // ceil(50000/256)
#define CVT_BLOCKS 6250   // 50000*128/(4*256)
#define OUT_BLOCKS 128    // 512*256 floats / (4*256)

typedef __attribute__((ext_vector_type(8))) short bf16x8;
typedef __attribute__((ext_vector_type(4))) float f32x4;

static __device__ __forceinline__ unsigned short f2b(float f) {
  __hip_bfloat16 h = __float2bfloat16(f);
  return *reinterpret_cast<unsigned short*>(&h);
}
static __device__ __forceinline__ float blo(unsigned int p) {
  return __uint_as_float(p << 16);
}
static __device__ __forceinline__ float bhi(unsigned int p) {
  return __uint_as_float(p & 0xffff0000u);
}

// ---------------- fused prep: zero deg + zero out + fp32->bf16 convert ----------------

__global__ __launch_bounds__(256) void k_prep(
    const float* __restrict__ x, unsigned short* __restrict__ xb,
    int* __restrict__ deg, float* __restrict__ out) {
  int b = blockIdx.x;
  if (b < NB_NODES) {
    int i = b * 256 + threadIdx.x;
    if (i < N_NODES) deg[i] = 0;
  } else if (b < NB_NODES + CVT_BLOCKS) {
    int i = ((b - NB_NODES) * 256 + threadIdx.x) * 4;
    if (i < N_NODES * D) {
      float4 f = *(const float4*)&x[i];
      ushort4 o = make_ushort4(f2b(f.x), f2b(f.y), f2b(f.z), f2b(f.w));
      *(ushort4*)&xb[i] = o;
    }
  } else {
    int i = ((b - NB_NODES - CVT_BLOCKS) * 256 + threadIdx.x) * 4;
    if (i < NUM_GRAPHS * 2 * D)
      *(float4*)&out[i] = make_float4(0.f, 0.f, 0.f, 0.f);
  }
}

// ---------------- CSR build ----------------

__global__ void k_count(const int* __restrict__ dst, int* __restrict__ deg) {
  int e = blockIdx.x * 256 + threadIdx.x;
  if (e < N_EDGES) atomicAdd(&deg[dst[e]], 1);
}

__global__ void k_scan1(const int* __restrict__ deg, int* __restrict__ bsum) {
  __shared__ int s[256];
  int t = threadIdx.x;
  int i = blockIdx.x * 256 + t;
  s[t] = (i < N_NODES) ? deg[i] : 0;
  __syncthreads();
  for (int off = 128; off > 0; off >>= 1) {
    if (t < off) s[t] += s[t + off];
    __syncthreads();
  }
  if (t == 0) bsum[blockIdx.x] = s[0];
}

__global__ void k_scan2(int* __restrict__ bsum, int nb) {
  __shared__ int s[256];
  int t = threadIdx.x;
  int v = (t < nb) ? bsum[t] : 0;
  s[t] = v;
  __syncthreads();
  for (int off = 1; off < 256; off <<= 1) {
    int add = (t >= off) ? s[t - off] : 0;
    __syncthreads();
    s[t] += add;
    __syncthreads();
  }
  if (t < nb) bsum[t] = s[t] - v;  // exclusive
}

__global__ void k_scan3(const int* __restrict__ deg, const int* __restrict__ bsum,
                        int* __restrict__ rowptr, int* __restrict__ pos) {
  __shared__ int s[256];
  int t = threadIdx.x;
  int i = blockIdx.x * 256 + t;
  int v = (i < N_NODES) ? deg[i] : 0;
  s[t] = v;
  __syncthreads();
  for (int off = 1; off < 256; off <<= 1) {
    int add = (t >= off) ? s[t - off] : 0;
    __syncthreads();
    s[t] += add;
    __syncthreads();
  }
  int excl = s[t] - v + bsum[blockIdx.x];
  if (i < N_NODES) { rowptr[i] = excl; pos[i] = excl; }
  if (i == N_NODES - 1) rowptr[N_NODES] = excl + v;
}

__global__ void k_bucket(const int* __restrict__ src, const int* __restrict__ dst,
                         int* __restrict__ pos, int* __restrict__ esrc) {
  int e = blockIdx.x * 256 + threadIdx.x;
  if (e < N_EDGES) {
    int slot = atomicAdd(&pos[dst[e]], 1);
    esrc[slot] = src[e];
  }
}

// ---------------- mean aggregation: one wave/node, 16 lanes x 16B per edge ----------------

__global__ __launch_bounds__(256) void k_agg(
    const unsigned short* __restrict__ xb, const int* __restrict__ rowptr,
    const int* __restrict__ esrc, unsigned short* __restrict__ aggb) {
  int node = (blockIdx.x * 256 + threadIdx.x) >> 6;
  int lane = threadIdx.x & 63;
  if (node >= N_NODES) return;
  const int q = lane >> 4;      // edge sub-slot 0..3
  const int c = lane & 15;      // col group: cols c*8..c*8+7
  int beg = rowptr[node], end = rowptr[node + 1];

  float acc[8];
#pragma unroll
  for (int i = 0; i < 8; ++i) acc[i] = 0.f;

  const uint4 Z = make_uint4(0, 0, 0, 0);
  for (int e = beg; e < end; e += 8) {
    int i0 = e + q, i1 = e + 4 + q;
    bool v0 = i0 < end, v1 = i1 < end;
    int s0 = v0 ? esrc[i0] : 0;
    int s1 = v1 ? esrc[i1] : 0;
    uint4 p0 = v0 ? *(const uint4*)&xb[(size_t)s0 * D + c * 8] : Z;
    uint4 p1 = v1 ? *(const uint4*)&xb[(size_t)s1 * D + c * 8] : Z;
    acc[0] += blo(p0.x) + blo(p1.x);
    acc[1] += bhi(p0.x) + bhi(p1.x);
    acc[2] += blo(p0.y) + blo(p1.y);
    acc[3] += bhi(p0.y) + bhi(p1.y);
    acc[4] += blo(p0.z) + blo(p1.z);
    acc[5] += bhi(p0.z) + bhi(p1.z);
    acc[6] += blo(p0.w) + blo(p1.w);
    acc[7] += bhi(p0.w) + bhi(p1.w);
  }

  // reduce across the 4 edge sub-slots (lanes c, c+16, c+32, c+48)
#pragma unroll
  for (int i = 0; i < 8; ++i) {
    acc[i] += __shfl_xor(acc[i], 16);
    acc[i] += __shfl_xor(acc[i], 32);
  }

  if (q == 0) {
    float inv = 1.f / fmaxf((float)(end - beg), 1.f);
    uint4 o;
    o.x = (unsigned int)f2b(acc[0] * inv) | ((unsigned int)f2b(acc[1] * inv) << 16);
    o.y = (unsigned int)f2b(acc[2] * inv) | ((unsigned int)f2b(acc[3] * inv) << 16);
    o.z = (unsigned int)f2b(acc[4] * inv) | ((unsigned int)f2b(acc[5] * inv) << 16);
    o.w = (unsigned int)f2b(acc[6] * inv) | ((unsigned int)f2b(acc[7] * inv) << 16);
    *(uint4*)&aggb[(size_t)node * D + c * 8] = o;
  }
}

// ---------------- MFMA GEMM: relu([Ab|Xb] @ [Wl|Wr]^T), fused segmented max-pool ----------------
// Yb may be nullptr (layer 2: x2 never materialized).

__global__ __launch_bounds__(512) void k_gemm(
    const unsigned short* __restrict__ Ab, const unsigned short* __restrict__ Xb,
    const float* __restrict__ Wl, const float* __restrict__ Wr,
    unsigned short* __restrict__ Yb, const int* __restrict__ batch,
    unsigned int* __restrict__ pool, int col_ofs) {
  __shared__ unsigned short Wlds[32768 + 256];  // 64KB weights/tile + 512B batch ids
  const int tid = threadIdx.x;
  const int w = tid >> 6, lane = tid & 63;
  const int lr = lane & 15, lh = lane >> 4;
  const int row0 = blockIdx.x * BM;
  const int row = row0 + w * 16 + lr;

  // A fragments: row `row`, k in [0,256): first half Ab, second half Xb
  bf16x8 a[8];
  if (row < N_NODES) {
    const unsigned short* ar = Ab + (size_t)row * D;
    const unsigned short* xr = Xb + (size_t)row * D;
#pragma unroll
    for (int kk = 0; kk < 4; ++kk)
      a[kk] = *(const bf16x8*)(ar + kk * 32 + lh * 8);
#pragma unroll
    for (int kk = 0; kk < 4; ++kk)
      a[4 + kk] = *(const bf16x8*)(xr + kk * 32 + lh * 8);
  } else {
#pragma unroll
    for (int kk = 0; kk < 8; ++kk)
      a[kk] = (bf16x8){0, 0, 0, 0, 0, 0, 0, 0};
  }

  // stage combined weight row j: k<128 from Wl, k>=128 from Wr; swizzle byte^=(j&7)<<4
  {
    int j = tid >> 2, quarter = tid & 3;
    const float* srcp = (quarter < 2) ? (Wl + j * D + quarter * 64)
                                      : (Wr + j * D + (quarter - 2) * 64);
#pragma unroll
    for (int q = 0; q < 8; ++q) {
      float4 f0 = *(const float4*)(srcp + q * 8);
      float4 f1 = *(const float4*)(srcp + q * 8 + 4);
      bf16x8 wv;
      wv[0] = (short)f2b(f0.x); wv[1] = (short)f2b(f0.y);
      wv[2] = (short)f2b(f0.z); wv[3] = (short)f2b(f0.w);
      wv[4] = (short)f2b(f1.x); wv[5] = (short)f2b(f1.y);
      wv[6] = (short)f2b(f1.z); wv[7] = (short)f2b(f1.w);
      int byteofs = j * 512 + ((quarter * 128 + q * 16) ^ ((j & 7) << 4));
      *(bf16x8*)((char*)Wlds + byteofs) = wv;
    }
  }
  __syncthreads();

  f32x4 acc[8];
#pragma unroll
  for (int jt = 0; jt < 8; ++jt) acc[jt] = (f32x4){0.f, 0.f, 0.f, 0.f};

#pragma unroll
  for (int jt = 0; jt < 8; ++jt) {
    int jj = jt * 16 + lr;
    const char* wbase = (const char*)Wlds + jj * 512;
    int sw = (jj & 7) << 4;
#pragma unroll
    for (int kk = 0; kk < 8; ++kk) {
      bf16x8 b = *(const bf16x8*)(wbase + ((kk * 64 + lh * 16) ^ sw));
      acc[jt] = __builtin_amdgcn_mfma_f32_16x16x32_bf16(a[kk], b, acc[jt], 0, 0, 0);
    }
  }

  __syncthreads();  // all waves done reading weights; reuse LDS for output tile
  // write relu(acc) as bf16 tile [128 rows][128 cols], swizzled
#pragma unroll
  for (int jt = 0; jt < 8; ++jt) {
#pragma unroll
    for (int r = 0; r < 4; ++r) {
      int rl = w * 16 + lh * 4 + r;
      int col = jt * 16 + lr;
      float v = acc[jt][r];
      v = v > 0.f ? v : 0.f;
      int byteofs = rl * 256 + ((col * 2) ^ ((rl & 7) << 4));
      *(unsigned short*)((char*)Wlds + byteofs) = f2b(v);
    }
  }
  // batch ids for this block's rows (separate LDS region)
  int* sb = (int*)(Wlds + 32768);
  if (tid < BM) {
    int grow = row0 + tid;
    sb[tid] = (grow < N_NODES) ? batch[grow] : -1;
  }
  __syncthreads();

  // coalesced bf16x8 stores (layer 1 only)
  if (Yb != nullptr) {
    int rl = tid >> 2, c0 = (tid & 3) * 64;  // c0 in bytes
    int grow = row0 + rl;
    if (grow < N_NODES) {
#pragma unroll
      for (int cc = 0; cc < 4; ++cc) {
        int byteofs = rl * 256 + ((c0 + cc * 16) ^ ((rl & 7) << 4));
        bf16x8 v = *(const bf16x8*)((char*)Wlds + byteofs);
        *(bf16x8*)&Yb[(size_t)grow * D + (c0 + cc * 16) / 2] = v;
      }
    }
  }

  // segmented max-pool: rows sorted by graph; ushort compare == float compare (relu >= 0)
  if (tid < 256) {
    int col = tid & 127;
    int r0 = (tid >> 7) * 64;
    unsigned short run = 0;
    int curg = sb[r0];
    for (int r = r0; r < r0 + 64; ++r) {
      int g = sb[r];
      if (g != curg) {
        if (curg >= 0 && run)
          atomicMax(&pool[curg * (2 * D) + col_ofs + col], ((unsigned int)run) << 16);
        curg = g;
        run = 0;
      }
      int byteofs = r * 256 + ((col * 2) ^ ((r & 7) << 4));
      unsigned short v = *(const unsigned short*)((char*)Wlds + byteofs);
      run = run > v ? run : v;
    }
    if (curg >= 0 && run)
      atomicMax(&pool[curg * (2 * D) + col_ofs + col], ((unsigned int)run) << 16);
  }
}

// ---------------- launch ----------------

extern "C" void kernel_launch(void* const* d_in, const int* in_sizes, int n_in,
                              void* d_out, int out_size, void* d_ws, size_t ws_size,
                              hipStream_t stream) {
  const float* x = (const float*)d_in[0];
  const int* ei = (const int*)d_in[1];
  const int* src = ei;               // edge_index[0]
  const int* dst = ei + N_EDGES;     // edge_index[1]
  const int* batch = (const int*)d_in[2];
  const float* Wl1 = (const float*)d_in[3];
  const float* Wr1 = (const float*)d_in[4];
  const float* Wl2 = (const float*)d_in[5];
  const float* Wr2 = (const float*)d_in[6];

  char* ws = (char*)d_ws;
  size_t off = 0;
  auto alloc = [&](size_t bytes) -> void* {
    void* p = ws + off;
    off += (bytes + 511) & ~(size_t)511;
    return p;
  };
  int* deg = (int*)alloc((size_t)N_NODES * 4);
  int* rowptr = (int*)alloc((size_t)(N_NODES + 1) * 4);
  int* pos = (int*)alloc((size_t)N_NODES * 4);
  int* bsum = (int*)alloc(256 * 4);
  int* esrc = (int*)alloc((size_t)N_EDGES * 4);
  unsigned short* xb = (unsigned short*)alloc((size_t)N_NODES * D * 2);
  unsigned short* aggb = (unsigned short*)alloc((size_t)N_NODES * D * 2);
  unsigned short* x1b = (unsigned short*)alloc((size_t)N_NODES * D * 2);
  (void)ws_size; (void)in_sizes; (void)n_in; (void)out_size;

  // prep: zero deg + zero out + cvt (no runtime fillBuffer in the graph)
  k_prep<<<NB_NODES + CVT_BLOCKS + OUT_BLOCKS, 256, 0, stream>>>(
      x, xb, deg, (float*)d_out);

  k_count<<<(N_EDGES + 255) / 256, 256, 0, stream>>>(dst, deg);
  k_scan1<<<NB_NODES, 256, 0, stream>>>(deg, bsum);
  k_scan2<<<1, 256, 0, stream>>>(bsum, NB_NODES);
  k_scan3<<<NB_NODES, 256, 0, stream>>>(deg, bsum, rowptr, pos);
  k_bucket<<<(N_EDGES + 255) / 256, 256, 0, stream>>>(src, dst, pos, esrc);

  int agg_blocks = (N_NODES * 64 + 255) / 256;
  int gemm_blocks = (N_NODES + BM - 1) / BM;  // 391

  // layer 1: pool x1 into cols [0,128)
  k_agg<<<agg_blocks, 256, 0, stream>>>(xb, rowptr, esrc, aggb);
  k_gemm<<<gemm_blocks, 512, 0, stream>>>(aggb, xb, Wl1, Wr1, x1b, batch,
                                          (unsigned int*)d_out, 0);
  // layer 2: x2 never materialized; pool into cols [128,256)
  k_agg<<<agg_blocks, 256, 0, stream>>>(x1b, rowptr, esrc, aggb);
  k_gemm<<<gemm_blocks, 512, 0, stream>>>(aggb, x1b, Wl2, Wr2, nullptr, batch,
                                          (unsigned int*)d_out, D);
}

// Round 8
// 158.266 us; speedup vs baseline: 1.1812x; 1.1812x over previous
//
#include <hip/hip_runtime.h>
#include <hip/hip_bf16.h>

#define N_NODES 50000
#define N_EDGES 500000
#define D 128
#define NUM_GRAPHS 512
#define BM 128
#define NB_NODES 196      // ceil(50000/256)
#define CVT_BLOCKS 6250   // 50000*128/(4*256)
#define OUT_BLOCKS 128    // 512*256 floats / (4*256)

typedef __attribute__((ext_vector_type(8))) short bf16x8;
typedef __attribute__((ext_vector_type(4))) float f32x4;

static __device__ __forceinline__ unsigned short f2b(float f) {
  __hip_bfloat16 h = __float2bfloat16(f);
  return *reinterpret_cast<unsigned short*>(&h);
}
static __device__ __forceinline__ float blo(unsigned int p) {
  return __uint_as_float(p << 16);
}
static __device__ __forceinline__ float bhi(unsigned int p) {
  return __uint_as_float(p & 0xffff0000u);
}

// ---------------- fused prep: zero deg + zero out + fp32->bf16 convert ----------------

__global__ __launch_bounds__(256) void k_prep(
    const float* __restrict__ x, unsigned short* __restrict__ xb,
    int* __restrict__ deg, float* __restrict__ out) {
  int b = blockIdx.x;
  if (b < NB_NODES) {
    int i = b * 256 + threadIdx.x;
    if (i < N_NODES) deg[i] = 0;
  } else if (b < NB_NODES + CVT_BLOCKS) {
    int i = ((b - NB_NODES) * 256 + threadIdx.x) * 4;
    if (i < N_NODES * D) {
      float4 f = *(const float4*)&x[i];
      ushort4 o = make_ushort4(f2b(f.x), f2b(f.y), f2b(f.z), f2b(f.w));
      *(ushort4*)&xb[i] = o;
    }
  } else {
    int i = ((b - NB_NODES - CVT_BLOCKS) * 256 + threadIdx.x) * 4;
    if (i < NUM_GRAPHS * 2 * D)
      *(float4*)&out[i] = make_float4(0.f, 0.f, 0.f, 0.f);
  }
}

// ---------------- CSR build ----------------

__global__ void k_count(const int* __restrict__ dst, int* __restrict__ deg) {
  int e = blockIdx.x * 256 + threadIdx.x;
  if (e < N_EDGES) atomicAdd(&deg[dst[e]], 1);
}

__global__ void k_scan1(const int* __restrict__ deg, int* __restrict__ bsum) {
  __shared__ int s[256];
  int t = threadIdx.x;
  int i = blockIdx.x * 256 + t;
  s[t] = (i < N_NODES) ? deg[i] : 0;
  __syncthreads();
  for (int off = 128; off > 0; off >>= 1) {
    if (t < off) s[t] += s[t + off];
    __syncthreads();
  }
  if (t == 0) bsum[blockIdx.x] = s[0];
}

__global__ void k_scan2(int* __restrict__ bsum, int nb) {
  __shared__ int s[256];
  int t = threadIdx.x;
  int v = (t < nb) ? bsum[t] : 0;
  s[t] = v;
  __syncthreads();
  for (int off = 1; off < 256; off <<= 1) {
    int add = (t >= off) ? s[t - off] : 0;
    __syncthreads();
    s[t] += add;
    __syncthreads();
  }
  if (t < nb) bsum[t] = s[t] - v;  // exclusive
}

__global__ void k_scan3(const int* __restrict__ deg, const int* __restrict__ bsum,
                        int* __restrict__ rowptr, int* __restrict__ pos) {
  __shared__ int s[256];
  int t = threadIdx.x;
  int i = blockIdx.x * 256 + t;
  int v = (i < N_NODES) ? deg[i] : 0;
  s[t] = v;
  __syncthreads();
  for (int off = 1; off < 256; off <<= 1) {
    int add = (t >= off) ? s[t - off] : 0;
    __syncthreads();
    s[t] += add;
    __syncthreads();
  }
  int excl = s[t] - v + bsum[blockIdx.x];
  if (i < N_NODES) { rowptr[i] = excl; pos[i] = excl; }
  if (i == N_NODES - 1) rowptr[N_NODES] = excl + v;
}

__global__ void k_bucket(const int* __restrict__ src, const int* __restrict__ dst,
                         int* __restrict__ pos, int* __restrict__ esrc) {
  int e = blockIdx.x * 256 + threadIdx.x;
  if (e < N_EDGES) {
    int slot = atomicAdd(&pos[dst[e]], 1);
    esrc[slot] = src[e];
  }
}

// ---------------- mean aggregation: one wave/node, 16 lanes x 16B per edge ----------------
// Per-lane exact loop bounds: every edge row is loaded exactly once (no padded loads).

__global__ __launch_bounds__(256) void k_agg(
    const unsigned short* __restrict__ xb, const int* __restrict__ rowptr,
    const int* __restrict__ esrc, unsigned short* __restrict__ aggb) {
  int node = (blockIdx.x * 256 + threadIdx.x) >> 6;
  int lane = threadIdx.x & 63;
  if (node >= N_NODES) return;
  const int q = lane >> 4;      // edge sub-slot 0..3
  const int c = lane & 15;      // col group: cols c*8..c*8+7
  int beg = rowptr[node], end = rowptr[node + 1];

  float acc[8];
#pragma unroll
  for (int i = 0; i < 8; ++i) acc[i] = 0.f;

  int e = beg + q;
  for (; e + 4 < end; e += 8) {   // both e and e+4 valid for this lane
    int s0 = esrc[e];
    int s1 = esrc[e + 4];
    uint4 p0 = *(const uint4*)&xb[(size_t)s0 * D + c * 8];
    uint4 p1 = *(const uint4*)&xb[(size_t)s1 * D + c * 8];
    acc[0] += blo(p0.x) + blo(p1.x);
    acc[1] += bhi(p0.x) + bhi(p1.x);
    acc[2] += blo(p0.y) + blo(p1.y);
    acc[3] += bhi(p0.y) + bhi(p1.y);
    acc[4] += blo(p0.z) + blo(p1.z);
    acc[5] += bhi(p0.z) + bhi(p1.z);
    acc[6] += blo(p0.w) + blo(p1.w);
    acc[7] += bhi(p0.w) + bhi(p1.w);
  }
  if (e < end) {                  // exact remainder (0 or 1 load per lane)
    int s0 = esrc[e];
    uint4 p0 = *(const uint4*)&xb[(size_t)s0 * D + c * 8];
    acc[0] += blo(p0.x);
    acc[1] += bhi(p0.x);
    acc[2] += blo(p0.y);
    acc[3] += bhi(p0.y);
    acc[4] += blo(p0.z);
    acc[5] += bhi(p0.z);
    acc[6] += blo(p0.w);
    acc[7] += bhi(p0.w);
  }

  // reduce across the 4 edge sub-slots (lanes c, c+16, c+32, c+48)
#pragma unroll
  for (int i = 0; i < 8; ++i) {
    acc[i] += __shfl_xor(acc[i], 16);
    acc[i] += __shfl_xor(acc[i], 32);
  }

  if (q == 0) {
    float inv = 1.f / fmaxf((float)(end - beg), 1.f);
    uint4 o;
    o.x = (unsigned int)f2b(acc[0] * inv) | ((unsigned int)f2b(acc[1] * inv) << 16);
    o.y = (unsigned int)f2b(acc[2] * inv) | ((unsigned int)f2b(acc[3] * inv) << 16);
    o.z = (unsigned int)f2b(acc[4] * inv) | ((unsigned int)f2b(acc[5] * inv) << 16);
    o.w = (unsigned int)f2b(acc[6] * inv) | ((unsigned int)f2b(acc[7] * inv) << 16);
    *(uint4*)&aggb[(size_t)node * D + c * 8] = o;
  }
}

// ---------------- MFMA GEMM: relu([Ab|Xb] @ [Wl|Wr]^T), fused segmented max-pool ----------------
// Yb may be nullptr (layer 2: x2 never materialized).

__global__ __launch_bounds__(512) void k_gemm(
    const unsigned short* __restrict__ Ab, const unsigned short* __restrict__ Xb,
    const float* __restrict__ Wl, const float* __restrict__ Wr,
    unsigned short* __restrict__ Yb, const int* __restrict__ batch,
    unsigned int* __restrict__ pool, int col_ofs) {
  __shared__ unsigned short Wlds[32768 + 256];  // 64KB weights/tile + 512B batch ids
  const int tid = threadIdx.x;
  const int w = tid >> 6, lane = tid & 63;
  const int lr = lane & 15, lh = lane >> 4;
  const int row0 = blockIdx.x * BM;
  const int row = row0 + w * 16 + lr;

  // A fragments: row `row`, k in [0,256): first half Ab, second half Xb
  bf16x8 a[8];
  if (row < N_NODES) {
    const unsigned short* ar = Ab + (size_t)row * D;
    const unsigned short* xr = Xb + (size_t)row * D;
#pragma unroll
    for (int kk = 0; kk < 4; ++kk)
      a[kk] = *(const bf16x8*)(ar + kk * 32 + lh * 8);
#pragma unroll
    for (int kk = 0; kk < 4; ++kk)
      a[4 + kk] = *(const bf16x8*)(xr + kk * 32 + lh * 8);
  } else {
#pragma unroll
    for (int kk = 0; kk < 8; ++kk)
      a[kk] = (bf16x8){0, 0, 0, 0, 0, 0, 0, 0};
  }

  // stage combined weight row j: k<128 from Wl, k>=128 from Wr; swizzle byte^=(j&7)<<4
  {
    int j = tid >> 2, quarter = tid & 3;
    const float* srcp = (quarter < 2) ? (Wl + j * D + quarter * 64)
                                      : (Wr + j * D + (quarter - 2) * 64);
#pragma unroll
    for (int q = 0; q < 8; ++q) {
      float4 f0 = *(const float4*)(srcp + q * 8);
      float4 f1 = *(const float4*)(srcp + q * 8 + 4);
      bf16x8 wv;
      wv[0] = (short)f2b(f0.x); wv[1] = (short)f2b(f0.y);
      wv[2] = (short)f2b(f0.z); wv[3] = (short)f2b(f0.w);
      wv[4] = (short)f2b(f1.x); wv[5] = (short)f2b(f1.y);
      wv[6] = (short)f2b(f1.z); wv[7] = (short)f2b(f1.w);
      int byteofs = j * 512 + ((quarter * 128 + q * 16) ^ ((j & 7) << 4));
      *(bf16x8*)((char*)Wlds + byteofs) = wv;
    }
  }
  __syncthreads();

  f32x4 acc[8];
#pragma unroll
  for (int jt = 0; jt < 8; ++jt) acc[jt] = (f32x4){0.f, 0.f, 0.f, 0.f};

#pragma unroll
  for (int jt = 0; jt < 8; ++jt) {
    int jj = jt * 16 + lr;
    const char* wbase = (const char*)Wlds + jj * 512;
    int sw = (jj & 7) << 4;
#pragma unroll
    for (int kk = 0; kk < 8; ++kk) {
      bf16x8 b = *(const bf16x8*)(wbase + ((kk * 64 + lh * 16) ^ sw));
      acc[jt] = __builtin_amdgcn_mfma_f32_16x16x32_bf16(a[kk], b, acc[jt], 0, 0, 0);
    }
  }

  __syncthreads();  // all waves done reading weights; reuse LDS for output tile
  // write relu(acc) as bf16 tile [128 rows][128 cols], swizzled
#pragma unroll
  for (int jt = 0; jt < 8; ++jt) {
#pragma unroll
    for (int r = 0; r < 4; ++r) {
      int rl = w * 16 + lh * 4 + r;
      int col = jt * 16 + lr;
      float v = acc[jt][r];
      v = v > 0.f ? v : 0.f;
      int byteofs = rl * 256 + ((col * 2) ^ ((rl & 7) << 4));
      *(unsigned short*)((char*)Wlds + byteofs) = f2b(v);
    }
  }
  // batch ids for this block's rows (separate LDS region)
  int* sb = (int*)(Wlds + 32768);
  if (tid < BM) {
    int grow = row0 + tid;
    sb[tid] = (grow < N_NODES) ? batch[grow] : -1;
  }
  __syncthreads();

  // coalesced bf16x8 stores (layer 1 only)
  if (Yb != nullptr) {
    int rl = tid >> 2, c0 = (tid & 3) * 64;  // c0 in bytes
    int grow = row0 + rl;
    if (grow < N_NODES) {
#pragma unroll
      for (int cc = 0; cc < 4; ++cc) {
        int byteofs = rl * 256 + ((c0 + cc * 16) ^ ((rl & 7) << 4));
        bf16x8 v = *(const bf16x8*)((char*)Wlds + byteofs);
        *(bf16x8*)&Yb[(size_t)grow * D + (c0 + cc * 16) / 2] = v;
      }
    }
  }

  // segmented max-pool: rows sorted by graph; ushort compare == float compare (relu >= 0)
  if (tid < 256) {
    int col = tid & 127;
    int r0 = (tid >> 7) * 64;
    unsigned short run = 0;
    int curg = sb[r0];
    for (int r = r0; r < r0 + 64; ++r) {
      int g = sb[r];
      if (g != curg) {
        if (curg >= 0 && run)
          atomicMax(&pool[curg * (2 * D) + col_ofs + col], ((unsigned int)run) << 16);
        curg = g;
        run = 0;
      }
      int byteofs = r * 256 + ((col * 2) ^ ((r & 7) << 4));
      unsigned short v = *(const unsigned short*)((char*)Wlds + byteofs);
      run = run > v ? run : v;
    }
    if (curg >= 0 && run)
      atomicMax(&pool[curg * (2 * D) + col_ofs + col], ((unsigned int)run) << 16);
  }
}

// ---------------- launch ----------------

extern "C" void kernel_launch(void* const* d_in, const int* in_sizes, int n_in,
                              void* d_out, int out_size, void* d_ws, size_t ws_size,
                              hipStream_t stream) {
  const float* x = (const float*)d_in[0];
  const int* ei = (const int*)d_in[1];
  const int* src = ei;               // edge_index[0]
  const int* dst = ei + N_EDGES;     // edge_index[1]
  const int* batch = (const int*)d_in[2];
  const float* Wl1 = (const float*)d_in[3];
  const float* Wr1 = (const float*)d_in[4];
  const float* Wl2 = (const float*)d_in[5];
  const float* Wr2 = (const float*)d_in[6];

  char* ws = (char*)d_ws;
  size_t off = 0;
  auto alloc = [&](size_t bytes) -> void* {
    void* p = ws + off;
    off += (bytes + 511) & ~(size_t)511;
    return p;
  };
  int* deg = (int*)alloc((size_t)N_NODES * 4);
  int* rowptr = (int*)alloc((size_t)(N_NODES + 1) * 4);
  int* pos = (int*)alloc((size_t)N_NODES * 4);
  int* bsum = (int*)alloc(256 * 4);
  int* esrc = (int*)alloc((size_t)N_EDGES * 4);
  unsigned short* xb = (unsigned short*)alloc((size_t)N_NODES * D * 2);
  unsigned short* aggb = (unsigned short*)alloc((size_t)N_NODES * D * 2);
  unsigned short* x1b = (unsigned short*)alloc((size_t)N_NODES * D * 2);
  (void)ws_size; (void)in_sizes; (void)n_in; (void)out_size;

  // prep: zero deg + zero out + cvt (no runtime fillBuffer in the graph)
  k_prep<<<NB_NODES + CVT_BLOCKS + OUT_BLOCKS, 256, 0, stream>>>(
      x, xb, deg, (float*)d_out);

  k_count<<<(N_EDGES + 255) / 256, 256, 0, stream>>>(dst, deg);
  k_scan1<<<NB_NODES, 256, 0, stream>>>(deg, bsum);
  k_scan2<<<1, 256, 0, stream>>>(bsum, NB_NODES);
  k_scan3<<<NB_NODES, 256, 0, stream>>>(deg, bsum, rowptr, pos);
  k_bucket<<<(N_EDGES + 255) / 256, 256, 0, stream>>>(src, dst, pos, esrc);

  int agg_blocks = (N_NODES * 64 + 255) / 256;
  int gemm_blocks = (N_NODES + BM - 1) / BM;  // 391

  // layer 1: pool x1 into cols [0,128)
  k_agg<<<agg_blocks, 256, 0, stream>>>(xb, rowptr, esrc, aggb);
  k_gemm<<<gemm_blocks, 512, 0, stream>>>(aggb, xb, Wl1, Wr1, x1b, batch,
                                          (unsigned int*)d_out, 0);
  // layer 2: x2 never materialized; pool into cols [128,256)
  k_agg<<<agg_blocks, 256, 0, stream>>>(x1b, rowptr, esrc, aggb);
  k_gemm<<<gemm_blocks, 512, 0, stream>>>(aggb, x1b, Wl2, Wr2, nullptr, batch,
                                          (unsigned int*)d_out, D);
}

// Round 9
// 139.412 us; speedup vs baseline: 1.3409x; 1.1352x over previous
//
#include <hip/hip_runtime.h>
#include <hip/hip_bf16.h>

#define N_NODES 50000
#define N_EDGES 500000
#define D 128
#define NUM_GRAPHS 512
#define BM 128
#define NB_NODES 196      // ceil(50000/256)
#define CVT_BLOCKS 6250   // 50000*128/(4*256)
#define OUT_BLOCKS 128    // 512*256 floats / (4*256)
#define WC_BLOCKS 16      // 128*256 bf16 / 256 threads / 8 elems

typedef __attribute__((ext_vector_type(8))) short bf16x8;
typedef __attribute__((ext_vector_type(4))) float f32x4;

static __device__ __forceinline__ unsigned short f2b(float f) {
  __hip_bfloat16 h = __float2bfloat16(f);
  return *reinterpret_cast<unsigned short*>(&h);
}
static __device__ __forceinline__ float blo(unsigned int p) {
  return __uint_as_float(p << 16);
}
static __device__ __forceinline__ float bhi(unsigned int p) {
  return __uint_as_float(p & 0xffff0000u);
}

// ---------------- fused prep: zero deg + zero out + cvt x + build swizzled weights ----------------

__global__ __launch_bounds__(256) void k_prep(
    const float* __restrict__ x, unsigned short* __restrict__ xb,
    int* __restrict__ deg, float* __restrict__ out,
    const float* __restrict__ Wl1, const float* __restrict__ Wr1,
    const float* __restrict__ Wl2, const float* __restrict__ Wr2,
    unsigned short* __restrict__ wc1, unsigned short* __restrict__ wc2) {
  int b = blockIdx.x;
  if (b < NB_NODES) {
    int i = b * 256 + threadIdx.x;
    if (i < N_NODES) deg[i] = 0;
  } else if (b < NB_NODES + CVT_BLOCKS) {
    int i = ((b - NB_NODES) * 256 + threadIdx.x) * 4;
    if (i < N_NODES * D) {
      float4 f = *(const float4*)&x[i];
      ushort4 o = make_ushort4(f2b(f.x), f2b(f.y), f2b(f.z), f2b(f.w));
      *(ushort4*)&xb[i] = o;
    }
  } else if (b < NB_NODES + CVT_BLOCKS + OUT_BLOCKS) {
    int i = ((b - NB_NODES - CVT_BLOCKS) * 256 + threadIdx.x) * 4;
    if (i < NUM_GRAPHS * 2 * D)
      *(float4*)&out[i] = make_float4(0.f, 0.f, 0.f, 0.f);
  } else {
    // combined [Wl|Wr] -> bf16, XOR-swizzled image: LDS-ready
    int b2 = b - NB_NODES - CVT_BLOCKS - OUT_BLOCKS;
    int layer = b2 >> 4;
    int idx = (b2 & 15) * 256 + threadIdx.x;   // 0..4095
    int j = idx >> 5;        // output row 0..127
    int kg = idx & 31;       // 8-elem k group, k0 = kg*8 in [0,256)
    int k0 = kg * 8;
    const float* wl = layer ? Wl2 : Wl1;
    const float* wr = layer ? Wr2 : Wr1;
    const float* srcp = (k0 < D) ? (wl + j * D + k0) : (wr + j * D + (k0 - D));
    float4 f0 = *(const float4*)srcp;
    float4 f1 = *(const float4*)(srcp + 4);
    bf16x8 wv;
    wv[0] = (short)f2b(f0.x); wv[1] = (short)f2b(f0.y);
    wv[2] = (short)f2b(f0.z); wv[3] = (short)f2b(f0.w);
    wv[4] = (short)f2b(f1.x); wv[5] = (short)f2b(f1.y);
    wv[6] = (short)f2b(f1.z); wv[7] = (short)f2b(f1.w);
    unsigned short* wc = layer ? wc2 : wc1;
    int byteofs = j * 512 + ((kg * 16) ^ ((j & 7) << 4));
    *(bf16x8*)((char*)wc + byteofs) = wv;
  }
}

// ---------------- CSR build ----------------

__global__ void k_count(const int* __restrict__ dst, int* __restrict__ deg) {
  int e = blockIdx.x * 256 + threadIdx.x;
  if (e < N_EDGES) atomicAdd(&deg[dst[e]], 1);
}

__global__ void k_scan1(const int* __restrict__ deg, int* __restrict__ bsum) {
  __shared__ int s[256];
  int t = threadIdx.x;
  int i = blockIdx.x * 256 + t;
  s[t] = (i < N_NODES) ? deg[i] : 0;
  __syncthreads();
  for (int off = 128; off > 0; off >>= 1) {
    if (t < off) s[t] += s[t + off];
    __syncthreads();
  }
  if (t == 0) bsum[blockIdx.x] = s[0];
}

__global__ void k_scan2(int* __restrict__ bsum, int nb) {
  __shared__ int s[256];
  int t = threadIdx.x;
  int v = (t < nb) ? bsum[t] : 0;
  s[t] = v;
  __syncthreads();
  for (int off = 1; off < 256; off <<= 1) {
    int add = (t >= off) ? s[t - off] : 0;
    __syncthreads();
    s[t] += add;
    __syncthreads();
  }
  if (t < nb) bsum[t] = s[t] - v;  // exclusive
}

__global__ void k_scan3(const int* __restrict__ deg, const int* __restrict__ bsum,
                        int* __restrict__ rowptr, int* __restrict__ pos) {
  __shared__ int s[256];
  int t = threadIdx.x;
  int i = blockIdx.x * 256 + t;
  int v = (i < N_NODES) ? deg[i] : 0;
  s[t] = v;
  __syncthreads();
  for (int off = 1; off < 256; off <<= 1) {
    int add = (t >= off) ? s[t - off] : 0;
    __syncthreads();
    s[t] += add;
    __syncthreads();
  }
  int excl = s[t] - v + bsum[blockIdx.x];
  if (i < N_NODES) { rowptr[i] = excl; pos[i] = excl; }
  if (i == N_NODES - 1) rowptr[N_NODES] = excl + v;
}

__global__ void k_bucket(const int* __restrict__ src, const int* __restrict__ dst,
                         int* __restrict__ pos, int* __restrict__ esrc) {
  int e = blockIdx.x * 256 + threadIdx.x;
  if (e < N_EDGES) {
    int slot = atomicAdd(&pos[dst[e]], 1);
    esrc[slot] = src[e];
  }
}

// ---------------- mean aggregation: one wave/node, 16 lanes x 16B per edge ----------------
// Per-lane exact loop bounds: every edge row is loaded exactly once (no padded loads).

__global__ __launch_bounds__(256) void k_agg(
    const unsigned short* __restrict__ xb, const int* __restrict__ rowptr,
    const int* __restrict__ esrc, unsigned short* __restrict__ aggb) {
  int node = (blockIdx.x * 256 + threadIdx.x) >> 6;
  int lane = threadIdx.x & 63;
  if (node >= N_NODES) return;
  const int q = lane >> 4;      // edge sub-slot 0..3
  const int c = lane & 15;      // col group: cols c*8..c*8+7
  int beg = rowptr[node], end = rowptr[node + 1];

  float acc[8];
#pragma unroll
  for (int i = 0; i < 8; ++i) acc[i] = 0.f;

  int e = beg + q;
  for (; e + 4 < end; e += 8) {   // both e and e+4 valid for this lane
    int s0 = esrc[e];
    int s1 = esrc[e + 4];
    uint4 p0 = *(const uint4*)&xb[(size_t)s0 * D + c * 8];
    uint4 p1 = *(const uint4*)&xb[(size_t)s1 * D + c * 8];
    acc[0] += blo(p0.x) + blo(p1.x);
    acc[1] += bhi(p0.x) + bhi(p1.x);
    acc[2] += blo(p0.y) + blo(p1.y);
    acc[3] += bhi(p0.y) + bhi(p1.y);
    acc[4] += blo(p0.z) + blo(p1.z);
    acc[5] += bhi(p0.z) + bhi(p1.z);
    acc[6] += blo(p0.w) + blo(p1.w);
    acc[7] += bhi(p0.w) + bhi(p1.w);
  }
  if (e < end) {                  // exact remainder (0 or 1 load per lane)
    int s0 = esrc[e];
    uint4 p0 = *(const uint4*)&xb[(size_t)s0 * D + c * 8];
    acc[0] += blo(p0.x);
    acc[1] += bhi(p0.x);
    acc[2] += blo(p0.y);
    acc[3] += bhi(p0.y);
    acc[4] += blo(p0.z);
    acc[5] += bhi(p0.z);
    acc[6] += blo(p0.w);
    acc[7] += bhi(p0.w);
  }

  // reduce across the 4 edge sub-slots (lanes c, c+16, c+32, c+48)
#pragma unroll
  for (int i = 0; i < 8; ++i) {
    acc[i] += __shfl_xor(acc[i], 16);
    acc[i] += __shfl_xor(acc[i], 32);
  }

  if (q == 0) {
    float inv = 1.f / fmaxf((float)(end - beg), 1.f);
    uint4 o;
    o.x = (unsigned int)f2b(acc[0] * inv) | ((unsigned int)f2b(acc[1] * inv) << 16);
    o.y = (unsigned int)f2b(acc[2] * inv) | ((unsigned int)f2b(acc[3] * inv) << 16);
    o.z = (unsigned int)f2b(acc[4] * inv) | ((unsigned int)f2b(acc[5] * inv) << 16);
    o.w = (unsigned int)f2b(acc[6] * inv) | ((unsigned int)f2b(acc[7] * inv) << 16);
    *(uint4*)&aggb[(size_t)node * D + c * 8] = o;
  }
}

// ---------------- MFMA GEMM: relu([Ab|Xb] @ Wc^T), fused segmented max-pool ----------------
// Wc is the pre-swizzled bf16 LDS image built by k_prep. Yb may be nullptr.

__global__ __launch_bounds__(512) void k_gemm(
    const unsigned short* __restrict__ Ab, const unsigned short* __restrict__ Xb,
    const unsigned short* __restrict__ Wc,
    unsigned short* __restrict__ Yb, const int* __restrict__ batch,
    unsigned int* __restrict__ pool, int col_ofs) {
  __shared__ unsigned short Wlds[32768 + 256];  // 64KB weights/tile + 512B batch ids
  const int tid = threadIdx.x;
  const int w = tid >> 6, lane = tid & 63;
  const int lr = lane & 15, lh = lane >> 4;
  const int row0 = blockIdx.x * BM;
  const int row = row0 + w * 16 + lr;

  // stage pre-swizzled weights: linear 64KB copy, fully coalesced
#pragma unroll
  for (int i = 0; i < 8; ++i) {
    int ofs = i * 8192 + tid * 16;
    *(bf16x8*)((char*)Wlds + ofs) = *(const bf16x8*)((const char*)Wc + ofs);
  }

  // A fragments: row `row`, k in [0,256): first half Ab, second half Xb
  bf16x8 a[8];
  if (row < N_NODES) {
    const unsigned short* ar = Ab + (size_t)row * D;
    const unsigned short* xr = Xb + (size_t)row * D;
#pragma unroll
    for (int kk = 0; kk < 4; ++kk)
      a[kk] = *(const bf16x8*)(ar + kk * 32 + lh * 8);
#pragma unroll
    for (int kk = 0; kk < 4; ++kk)
      a[4 + kk] = *(const bf16x8*)(xr + kk * 32 + lh * 8);
  } else {
#pragma unroll
    for (int kk = 0; kk < 8; ++kk)
      a[kk] = (bf16x8){0, 0, 0, 0, 0, 0, 0, 0};
  }
  __syncthreads();

  f32x4 acc[8];
#pragma unroll
  for (int jt = 0; jt < 8; ++jt) acc[jt] = (f32x4){0.f, 0.f, 0.f, 0.f};

#pragma unroll
  for (int jt = 0; jt < 8; ++jt) {
    int jj = jt * 16 + lr;
    const char* wbase = (const char*)Wlds + jj * 512;
    int sw = (jj & 7) << 4;
#pragma unroll
    for (int kk = 0; kk < 8; ++kk) {
      bf16x8 b = *(const bf16x8*)(wbase + ((kk * 64 + lh * 16) ^ sw));
      acc[jt] = __builtin_amdgcn_mfma_f32_16x16x32_bf16(a[kk], b, acc[jt], 0, 0, 0);
    }
  }

  __syncthreads();  // all waves done reading weights; reuse LDS for output tile
  // write relu(acc) as bf16 tile [128 rows][128 cols], swizzled
#pragma unroll
  for (int jt = 0; jt < 8; ++jt) {
#pragma unroll
    for (int r = 0; r < 4; ++r) {
      int rl = w * 16 + lh * 4 + r;
      int col = jt * 16 + lr;
      float v = acc[jt][r];
      v = v > 0.f ? v : 0.f;
      int byteofs = rl * 256 + ((col * 2) ^ ((rl & 7) << 4));
      *(unsigned short*)((char*)Wlds + byteofs) = f2b(v);
    }
  }
  // batch ids for this block's rows (separate LDS region)
  int* sb = (int*)(Wlds + 32768);
  if (tid < BM) {
    int grow = row0 + tid;
    sb[tid] = (grow < N_NODES) ? batch[grow] : -1;
  }
  __syncthreads();

  // coalesced bf16x8 stores (layer 1 only)
  if (Yb != nullptr) {
    int rl = tid >> 2, c0 = (tid & 3) * 64;  // c0 in bytes
    int grow = row0 + rl;
    if (grow < N_NODES) {
#pragma unroll
      for (int cc = 0; cc < 4; ++cc) {
        int byteofs = rl * 256 + ((c0 + cc * 16) ^ ((rl & 7) << 4));
        bf16x8 v = *(const bf16x8*)((char*)Wlds + byteofs);
        *(bf16x8*)&Yb[(size_t)grow * D + (c0 + cc * 16) / 2] = v;
      }
    }
  }

  // segmented max-pool: all 512 threads, 32-row chunks
  // rows sorted by graph; ushort compare == float compare (relu >= 0)
  {
    int col = tid & 127;
    int r0 = (tid >> 7) * 32;
    unsigned short run = 0;
    int curg = sb[r0];
    for (int r = r0; r < r0 + 32; ++r) {
      int g = sb[r];
      if (g != curg) {
        if (curg >= 0 && run)
          atomicMax(&pool[curg * (2 * D) + col_ofs + col], ((unsigned int)run) << 16);
        curg = g;
        run = 0;
      }
      int byteofs = r * 256 + ((col * 2) ^ ((r & 7) << 4));
      unsigned short v = *(const unsigned short*)((char*)Wlds + byteofs);
      run = run > v ? run : v;
    }
    if (curg >= 0 && run)
      atomicMax(&pool[curg * (2 * D) + col_ofs + col], ((unsigned int)run) << 16);
  }
}

// ---------------- launch ----------------

extern "C" void kernel_launch(void* const* d_in, const int* in_sizes, int n_in,
                              void* d_out, int out_size, void* d_ws, size_t ws_size,
                              hipStream_t stream) {
  const float* x = (const float*)d_in[0];
  const int* ei = (const int*)d_in[1];
  const int* src = ei;               // edge_index[0]
  const int* dst = ei + N_EDGES;     // edge_index[1]
  const int* batch = (const int*)d_in[2];
  const float* Wl1 = (const float*)d_in[3];
  const float* Wr1 = (const float*)d_in[4];
  const float* Wl2 = (const float*)d_in[5];
  const float* Wr2 = (const float*)d_in[6];

  char* ws = (char*)d_ws;
  size_t off = 0;
  auto alloc = [&](size_t bytes) -> void* {
    void* p = ws + off;
    off += (bytes + 511) & ~(size_t)511;
    return p;
  };
  int* deg = (int*)alloc((size_t)N_NODES * 4);
  int* rowptr = (int*)alloc((size_t)(N_NODES + 1) * 4);
  int* pos = (int*)alloc((size_t)N_NODES * 4);
  int* bsum = (int*)alloc(256 * 4);
  int* esrc = (int*)alloc((size_t)N_EDGES * 4);
  unsigned short* xb = (unsigned short*)alloc((size_t)N_NODES * D * 2);
  unsigned short* aggb = (unsigned short*)alloc((size_t)N_NODES * D * 2);
  unsigned short* x1b = (unsigned short*)alloc((size_t)N_NODES * D * 2);
  unsigned short* wc1 = (unsigned short*)alloc(65536);
  unsigned short* wc2 = (unsigned short*)alloc(65536);
  (void)ws_size; (void)in_sizes; (void)n_in; (void)out_size;

  // prep: zero deg + cvt x + zero out + build swizzled weight images
  k_prep<<<NB_NODES + CVT_BLOCKS + OUT_BLOCKS + 2 * WC_BLOCKS, 256, 0, stream>>>(
      x, xb, deg, (float*)d_out, Wl1, Wr1, Wl2, Wr2, wc1, wc2);

  k_count<<<(N_EDGES + 255) / 256, 256, 0, stream>>>(dst, deg);
  k_scan1<<<NB_NODES, 256, 0, stream>>>(deg, bsum);
  k_scan2<<<1, 256, 0, stream>>>(bsum, NB_NODES);
  k_scan3<<<NB_NODES, 256, 0, stream>>>(deg, bsum, rowptr, pos);
  k_bucket<<<(N_EDGES + 255) / 256, 256, 0, stream>>>(src, dst, pos, esrc);

  int agg_blocks = (N_NODES * 64 + 255) / 256;
  int gemm_blocks = (N_NODES + BM - 1) / BM;  // 391

  // layer 1: pool x1 into cols [0,128)
  k_agg<<<agg_blocks, 256, 0, stream>>>(xb, rowptr, esrc, aggb);
  k_gemm<<<gemm_blocks, 512, 0, stream>>>(aggb, xb, wc1, x1b, batch,
                                          (unsigned int*)d_out, 0);
  // layer 2: x2 never materialized; pool into cols [128,256)
  k_agg<<<agg_blocks, 256, 0, stream>>>(x1b, rowptr, esrc, aggb);
  k_gemm<<<gemm_blocks, 512, 0, stream>>>(aggb, x1b, wc2, nullptr, batch,
                                          (unsigned int*)d_out, D);
}